// Round 3
// baseline (420.680 us; speedup 1.0000x reference)
//
#include <hip/hip_runtime.h>
#include <stdint.h>

typedef __attribute__((ext_vector_type(4))) int int4v;
typedef __attribute__((ext_vector_type(4))) uint32_t uint4v;

#define M_DIM 8192
#define N_DIM 4096
#define K_DIM 4096

// K-permuted layout: within each 64-byte K chunk, stored byte p holds
// original k = (p>>2) + 16*(p&3).  Applied identically to A and B, so the
// MFMA dot-product (sum over k) is unchanged and the GEMM kernel needs no
// knowledge of the permutation.

// ---------------- pack x: int32 -> int8, K-permuted ----------------
// one thread = one 16-B output (words w0..w0+3 of one 64-k chunk)
__global__ void pack_a_perm(const int* __restrict__ x, uint4v* __restrict__ a8) {
    const int g = blockIdx.x * blockDim.x + threadIdx.x;  // global 16-B word index
    const int w0 = (g & 3) * 4;                           // word slot within chunk
    const int chunk = g >> 2;                             // 64-element k chunk
    const int* base = x + (size_t)chunk * 64;
    int4v L[4];
#pragma unroll
    for (int j = 0; j < 4; ++j) L[j] = *(const int4v*)(base + j * 16 + w0);
    uint4v outv;
#pragma unroll
    for (int wi = 0; wi < 4; ++wi) {
        outv[wi] = (uint32_t)(L[0][wi] & 0xff) | ((uint32_t)(L[1][wi] & 0xff) << 8) |
                   ((uint32_t)(L[2][wi] & 0xff) << 16) | ((uint32_t)(L[3][wi] & 0xff) << 24);
    }
    a8[g] = outv;
}

// ------- transpose+pack weight: [K][N] int32 -> Bt[N][K-permuted] int8 -------
// LDS-free: 16 coalesced dword loads -> register pack -> one 16-B store.
__global__ void transpose_b_perm(const int* __restrict__ w, int8_t* __restrict__ bt) {
    const int t = threadIdx.x;
    const int kt = blockIdx.y * 64;  // k chunk base
    const int n0 = blockIdx.x * 64;  // n tile base
    const int c4 = t & 3;            // which 16-B slot of the 64-B chunk row
    const int n = t >> 2;            // 0..63
    const int w0 = c4 * 4;
    const int* col = w + (size_t)kt * N_DIM + n0 + n;
    uint4v outv;
#pragma unroll
    for (int wi = 0; wi < 4; ++wi) {
        uint32_t p = 0;
#pragma unroll
        for (int j = 0; j < 4; ++j) {
            uint32_t b = (uint32_t)(col[(size_t)(w0 + wi + 16 * j) * N_DIM] & 0xff);
            p |= b << (8 * j);
        }
        outv[wi] = p;
    }
    *(uint4v*)&bt[(size_t)(n0 + n) * K_DIM + kt + w0 * 4] = outv;
}

// ---------------- GEMM: m97 structure, i8 MFMA (unchanged) ----------------
__device__ inline void async16(const void* g, void* l) {
    __builtin_amdgcn_global_load_lds(
        (const __attribute__((address_space(1))) uint32_t*)g,
        (__attribute__((address_space(3))) uint32_t*)l, 16, 0, 0);
}

__global__ void __launch_bounds__(256)
gemm_kernel(const int8_t* __restrict__ A, const int8_t* __restrict__ Bt,
            const float* __restrict__ pa, const float* __restrict__ pb,
            int* __restrict__ out) {
    __shared__ int8_t smem[16384];
    int8_t* As = smem;          // [128][64] bytes
    int8_t* Bs = smem + 8192;   // [128][64] bytes

    const int t = threadIdx.x;
    const int lane = t & 63;
    const int wave = t >> 6;
    const int m0 = blockIdx.y * 128;
    const int n0 = blockIdx.x * 128;
    const int wm = (wave >> 1) * 64;
    const int wn = (wave & 1) * 64;
    const float scale = pa[0] * pb[0];

    int4v acc[4][4];
    int4v zero = {0, 0, 0, 0};
#pragma unroll
    for (int i = 0; i < 4; ++i)
#pragma unroll
        for (int j = 0; j < 4; ++j) acc[i][j] = zero;

    const int rA = lane >> 2;           // row within 16-row group
    const int cA = (lane & 3) * 16;     // byte offset within 64 B row
    const int koff = (lane >> 4) * 16;  // fragment k byte offset
    const int fr = lane & 15;           // fragment row

    for (int kt = 0; kt < K_DIM; kt += 64) {
        __syncthreads();
#pragma unroll
        for (int i = 0; i < 2; ++i) {
            int rb = wave * 16 + i * 64;  // wave-uniform base row
            async16(A + (size_t)(m0 + rb + rA) * K_DIM + kt + cA, As + rb * 64);
            async16(Bt + (size_t)(n0 + rb + rA) * K_DIM + kt + cA, Bs + rb * 64);
        }
        __syncthreads();

        int4v af[4], bf[4];
#pragma unroll
        for (int i = 0; i < 4; ++i) {
            af[i] = *(const int4v*)&As[(wm + i * 16 + fr) * 64 + koff];
            bf[i] = *(const int4v*)&Bs[(wn + i * 16 + fr) * 64 + koff];
        }
#pragma unroll
        for (int i = 0; i < 4; ++i)
#pragma unroll
            for (int j = 0; j < 4; ++j)
                acc[i][j] = __builtin_amdgcn_mfma_i32_16x16x64_i8(af[i], bf[j],
                                                                  acc[i][j], 0, 0, 0);
    }

    const int orow = (lane >> 4) * 4;
    const int ocol = lane & 15;
#pragma unroll
    for (int i = 0; i < 4; ++i)
#pragma unroll
        for (int j = 0; j < 4; ++j)
#pragma unroll
            for (int r = 0; r < 4; ++r) {
                float v = (float)acc[i][j][r] * scale;
                v = rintf(v);
                v = fminf(127.f, fmaxf(-128.f, v));
                out[(size_t)(m0 + wm + i * 16 + orow + r) * N_DIM +
                    (n0 + wn + j * 16 + ocol)] = (int)v;
            }
}

extern "C" void kernel_launch(void* const* d_in, const int* in_sizes, int n_in,
                              void* d_out, int out_size, void* d_ws, size_t ws_size,
                              hipStream_t stream) {
    const int* x = (const int*)d_in[0];
    const int* w = (const int*)d_in[1];
    const float* pa = (const float*)d_in[2];
    const float* pb = (const float*)d_in[3];
    int* out = (int*)d_out;

    int8_t* a8 = (int8_t*)d_ws;                       // 32 MiB
    int8_t* bt8 = a8 + (size_t)M_DIM * K_DIM;         // 16 MiB

    const int nwords_a = M_DIM * K_DIM / 16;          // 16-B words in A
    pack_a_perm<<<nwords_a / 256, 256, 0, stream>>>(x, (uint4v*)a8);
    transpose_b_perm<<<dim3(N_DIM / 64, K_DIM / 64), 256, 0, stream>>>(w, bt8);
    gemm_kernel<<<dim3(N_DIM / 128, M_DIM / 128), 256, 0, stream>>>(a8, bt8, pa, pb, out);
}

// Round 4
// 402.217 us; speedup vs baseline: 1.0459x; 1.0459x over previous
//
#include <hip/hip_runtime.h>
#include <stdint.h>

typedef __attribute__((ext_vector_type(4))) int int4v;
typedef __attribute__((ext_vector_type(16))) int int16v;
typedef __attribute__((ext_vector_type(4))) uint32_t uint4v;

#define M_DIM 8192
#define N_DIM 4096
#define K_DIM 4096

// K-permuted layout: within each 64-byte K chunk, stored byte p holds
// original k = (p>>2) + 16*(p&3). Applied identically to A and B => MFMA
// dot products unchanged. GEMM additionally XOR-swizzles 16-B chunks within
// each 128-B LDS row (slot = chunk ^ (row&7)) to kill bank conflicts; the
// swizzle is applied in the global source address at staging and inverted
// at fragment-read time, so prep kernels don't know about it.

// ---------------- pack x: int32 -> int8, K-permuted ----------------
__global__ void pack_a_perm(const int* __restrict__ x, uint4v* __restrict__ a8) {
    const int g = blockIdx.x * blockDim.x + threadIdx.x;  // global 16-B word index
    const int w0 = (g & 3) * 4;                           // word slot within chunk
    const int chunk = g >> 2;                             // 64-element k chunk
    const int* base = x + (size_t)chunk * 64;
    int4v L[4];
#pragma unroll
    for (int j = 0; j < 4; ++j) L[j] = *(const int4v*)(base + j * 16 + w0);
    uint4v outv;
#pragma unroll
    for (int wi = 0; wi < 4; ++wi) {
        outv[wi] = (uint32_t)(L[0][wi] & 0xff) | ((uint32_t)(L[1][wi] & 0xff) << 8) |
                   ((uint32_t)(L[2][wi] & 0xff) << 16) | ((uint32_t)(L[3][wi] & 0xff) << 24);
    }
    a8[g] = outv;
}

// ------- transpose+pack weight: [K][N] int32 -> Bt[N][K-permuted] int8 -------
__global__ void transpose_b_perm(const int* __restrict__ w, int8_t* __restrict__ bt) {
    const int t = threadIdx.x;
    const int kt = blockIdx.y * 64;
    const int n0 = blockIdx.x * 64;
    const int c4 = t & 3;
    const int n = t >> 2;
    const int w0 = c4 * 4;
    const int* col = w + (size_t)kt * N_DIM + n0 + n;
    uint4v outv;
#pragma unroll
    for (int wi = 0; wi < 4; ++wi) {
        uint32_t p = 0;
#pragma unroll
        for (int j = 0; j < 4; ++j) {
            uint32_t b = (uint32_t)(col[(size_t)(w0 + wi + 16 * j) * N_DIM] & 0xff);
            p |= b << (8 * j);
        }
        outv[wi] = p;
    }
    *(uint4v*)&bt[(size_t)(n0 + n) * K_DIM + kt + w0 * 4] = outv;
}

// ---------------- GEMM: BK=128, 32x32x32 i8, swizzled LDS ----------------
__device__ inline void async16(const void* g, void* l) {
    __builtin_amdgcn_global_load_lds(
        (const __attribute__((address_space(1))) uint32_t*)g,
        (__attribute__((address_space(3))) uint32_t*)l, 16, 0, 0);
}

__global__ void __launch_bounds__(256)
gemm_kernel(const int8_t* __restrict__ A, const int8_t* __restrict__ Bt,
            const float* __restrict__ pa, const float* __restrict__ pb,
            int* __restrict__ out) {
    __shared__ int8_t smem[32768];
    int8_t* As = smem;            // [128 rows][128 B], chunk-swizzled
    int8_t* Bs = smem + 16384;

    const int t = threadIdx.x;
    const int lane = t & 63;
    const int wave = t >> 6;
    const int m0 = blockIdx.y * 128;
    const int n0 = blockIdx.x * 128;
    const int wm = (wave >> 1) * 64;
    const int wn = (wave & 1) * 64;
    const float scale = pa[0] * pb[0];

    int16v acc[2][2];
#pragma unroll
    for (int i = 0; i < 2; ++i)
#pragma unroll
        for (int j = 0; j < 2; ++j)
#pragma unroll
            for (int r = 0; r < 16; ++r) acc[i][j][r] = 0;

    const int srow = lane >> 3;   // row within 8-row staging group
    const int sslot = lane & 7;   // 16-B slot within 128-B row

    const int fm0 = wm + (lane & 31);       // A frag row, i*32 added in loop
    const int fn0 = wn + (lane & 31);       // B frag row
    const int fg = lane >> 5;               // k-half within 32-B MFMA window

    for (int kt = 0; kt < K_DIM; kt += 128) {
        __syncthreads();
#pragma unroll
        for (int s = 0; s < 4; ++s) {
            const int base_row = wave * 8 + s * 32;   // wave-uniform
            const int row = base_row + srow;
            const int cA = (sslot ^ (row & 7)) * 16;  // swizzled source chunk
            async16(A + (size_t)(m0 + row) * K_DIM + kt + cA, As + base_row * 128);
            async16(Bt + (size_t)(n0 + row) * K_DIM + kt + cA, Bs + base_row * 128);
        }
        __syncthreads();

#pragma unroll
        for (int ks = 0; ks < 4; ++ks) {
            int4v af[2], bf[2];
            const int cc = ks * 2 + fg;
#pragma unroll
            for (int i = 0; i < 2; ++i) {
                const int ra = fm0 + i * 32;
                af[i] = *(const int4v*)&As[ra * 128 + ((cc ^ (ra & 7)) * 16)];
                const int rb = fn0 + i * 32;
                bf[i] = *(const int4v*)&Bs[rb * 128 + ((cc ^ (rb & 7)) * 16)];
            }
#pragma unroll
            for (int i = 0; i < 2; ++i)
#pragma unroll
                for (int j = 0; j < 2; ++j)
                    acc[i][j] = __builtin_amdgcn_mfma_i32_32x32x32_i8(af[i], bf[j],
                                                                       acc[i][j], 0, 0, 0);
        }
    }

    const int col = lane & 31;
    const int rbase = (lane >> 5) * 4;
#pragma unroll
    for (int i = 0; i < 2; ++i)
#pragma unroll
        for (int j = 0; j < 2; ++j)
#pragma unroll
            for (int r = 0; r < 16; ++r) {
                const int rowf = rbase + (r & 3) + 8 * (r >> 2);
                float v = (float)acc[i][j][r] * scale;
                v = rintf(v);
                v = fminf(127.f, fmaxf(-128.f, v));
                out[(size_t)(m0 + wm + i * 32 + rowf) * N_DIM +
                    (n0 + wn + j * 32 + col)] = (int)v;
            }
}

extern "C" void kernel_launch(void* const* d_in, const int* in_sizes, int n_in,
                              void* d_out, int out_size, void* d_ws, size_t ws_size,
                              hipStream_t stream) {
    const int* x = (const int*)d_in[0];
    const int* w = (const int*)d_in[1];
    const float* pa = (const float*)d_in[2];
    const float* pb = (const float*)d_in[3];
    int* out = (int*)d_out;

    int8_t* a8 = (int8_t*)d_ws;                       // 32 MiB
    int8_t* bt8 = a8 + (size_t)M_DIM * K_DIM;         // 16 MiB

    const int nwords_a = M_DIM * K_DIM / 16;
    pack_a_perm<<<nwords_a / 256, 256, 0, stream>>>(x, (uint4v*)a8);
    transpose_b_perm<<<dim3(N_DIM / 64, K_DIM / 64), 256, 0, stream>>>(w, bt8);
    gemm_kernel<<<dim3(N_DIM / 128, M_DIM / 128), 256, 0, stream>>>(a8, bt8, pa, pb, out);
}